// Round 1
// baseline (256.293 us; speedup 1.0000x reference)
//
#include <hip/hip_runtime.h>
#include <hip/hip_bf16.h>

// MinGRU forward: z=sigmoid(xWz^T), h~=xWh^T, a=1-z+1e-8, b=z*h~, scan h=a*h+b.
// B=4 T=4096 D=1024.
// R4: (1) GEMM BK=64 -- two k-slices per barrier pair, halving the
// sync+vmcnt(0) drain events (occupancy is VGPR-pinned at 2 blocks/CU, so the
// 48KB LDS costs nothing). (2) Scan chunk CH 32->16 (NC=256): pass3 now has
// 1024 blocks (4 waves/SIMD, 2x TLP) and a 16-step dependent chain (2x
// shorter) -- it was latency-bound at 2 waves/SIMD. Epilogue chunk composition
// simplifies: one 16-row fragment == one chunk (q-lane scan only, no pair
// compose). pass2 handles 4 chunks/lane. Hstart aliases Aprod (safe: each
// pass2 thread reads its own cells before overwriting; no __restrict__ there).

typedef __bf16 bf16x8 __attribute__((ext_vector_type(8)));
typedef __bf16 bf16x4 __attribute__((ext_vector_type(4)));
typedef float  f32x4  __attribute__((ext_vector_type(4)));

#define BSZ 4
#define TSZ 4096
#define DSZ 1024
#define MSZ (BSZ*TSZ)      // 16384 rows
#define CH  16             // scan chunk length
#define NC  (TSZ/CH)       // 256 chunks per sequence

__device__ __forceinline__ void gload_lds16(const __bf16* g, __bf16* l) {
  __builtin_amdgcn_global_load_lds(
      (const __attribute__((address_space(1))) void*)g,
      (__attribute__((address_space(3))) void*)l, 16, 0, 0);
}

// ---------------- conversion: fp32 row-major -> bf16 fragment-tiled ----------------
// tiled layout: [rowblk][kblk:32][i:8][l:64][j:8] where
//   row = rowblk*128 + i*16 + (l&15), k = kblk*32 + (l>>4)*8 + j
__global__ void convert_tile_kernel(const float* __restrict__ X,
                                    const float* __restrict__ Wz,
                                    const float* __restrict__ Wh,
                                    __bf16* __restrict__ Xc,
                                    __bf16* __restrict__ Wzc,
                                    __bf16* __restrict__ Whc)
{
  const int bx = blockIdx.x;
  const float* src; __bf16* dst; int gid;
  if (bx < 8192)      { src = X;  dst = Xc;  gid =  bx        *256 + threadIdx.x; }
  else if (bx < 8704) { src = Wz; dst = Wzc; gid = (bx - 8192)*256 + threadIdx.x; }
  else                { src = Wh; dst = Whc; gid = (bx - 8704)*256 + threadIdx.x; }
  const int l    = gid & 63;
  const int i    = (gid >> 6) & 7;
  const int kblk = (gid >> 9) & 31;
  const int rblk = gid >> 14;
  const int row  = rblk*128 + i*16 + (l & 15);
  const int col  = kblk*32 + (l >> 4)*8;
  const float* g = src + (size_t)row*DSZ + col;
  float4 v0 = *(const float4*)g;
  float4 v1 = *(const float4*)(g + 4);
  bf16x8 p;
  p[0]=(__bf16)v0.x; p[1]=(__bf16)v0.y; p[2]=(__bf16)v0.z; p[3]=(__bf16)v0.w;
  p[4]=(__bf16)v1.x; p[5]=(__bf16)v1.y; p[6]=(__bf16)v1.z; p[7]=(__bf16)v1.w;
  *(bf16x8*)(dst + (size_t)gid*8) = p;
}

// ---------------- GEMM + gate epilogue + fused per-chunk composition ------------
// block tile 128(M) x 128(N), BK=64; 256 threads = 4 waves in 2x2, each wave 64x64.
__global__ __launch_bounds__(256, 2) void gemm_gate_kernel(
    const __bf16* __restrict__ Xc,  const __bf16* __restrict__ Wzc,
    const __bf16* __restrict__ Whc,
    const float* __restrict__ bz, const float* __restrict__ bh,
    __bf16* __restrict__ a_ws, float* __restrict__ b_out,
    float* __restrict__ Aprod, float* __restrict__ Bcomp)
{
  __shared__ __align__(16) __bf16 As [8192];
  __shared__ __align__(16) __bf16 Bzs[8192];
  __shared__ __align__(16) __bf16 Bhs[8192];

  const int tid  = threadIdx.x;
  const int lane = tid & 63;
  const int wv   = tid >> 6;
  const int wM   = (wv >> 1) * 64;
  const int wN   = (wv & 1) * 64;
  const int wMg  = wM >> 4;
  const int wNg  = wN >> 4;
  const int lr   = lane & 15;
  const int q    = lane >> 4;
  const int wbase = wv * 64;           // wave-uniform

  const __bf16* Xb = Xc  + (size_t)blockIdx.x * 32 * 4096;
  const __bf16* Zb = Wzc + (size_t)blockIdx.y * 32 * 4096;
  const __bf16* Hb = Whc + (size_t)blockIdx.y * 32 * 4096;

  f32x4 accz[4][4] = {};
  f32x4 acch[4][4] = {};

  for (int kblk = 0; kblk < 16; ++kblk) {   // BK=64: two 32-wide k-slices per iter
    __syncthreads();
    const size_t tb = (size_t)kblk * 8192;
    #pragma unroll
    for (int c = 0; c < 4; ++c) {
      const int eo = (c*256 + wbase + lane) * 8;  // per-lane global elem offset
      const int lo = (c*256 + wbase) * 8;         // wave-uniform LDS elem offset
      gload_lds16(Xb + tb + eo, As  + lo);
      gload_lds16(Zb + tb + eo, Bzs + lo);
      gload_lds16(Hb + tb + eo, Bhs + lo);
    }
    __syncthreads();

    #pragma unroll
    for (int h = 0; h < 2; ++h) {
      const int ho = h * 4096;                    // select k-slice within LDS
      bf16x8 af[4];
      #pragma unroll
      for (int i = 0; i < 4; ++i)
        af[i] = *(const bf16x8*)(As + ho + (wMg + i)*512 + lane*8);
      #pragma unroll
      for (int j = 0; j < 4; ++j) {
        bf16x8 bz8 = *(const bf16x8*)(Bzs + ho + (wNg + j)*512 + lane*8);
        bf16x8 bh8 = *(const bf16x8*)(Bhs + ho + (wNg + j)*512 + lane*8);
        #pragma unroll
        for (int i = 0; i < 4; ++i) {
          accz[j][i] = __builtin_amdgcn_mfma_f32_16x16x32_bf16(af[i], bz8, accz[j][i], 0, 0, 0);
          acch[j][i] = __builtin_amdgcn_mfma_f32_16x16x32_bf16(af[i], bh8, acch[j][i], 0, 0, 0);
        }
      }
    }
  }

  // ---- epilogue: gate + store + fused per-chunk affine composition ----
  // C/D layout col=lane&15, row=(lane>>4)*4+reg (verified m89/m91).
  // Lane's 4 regs of tile i cover rows wM+i*16+q*4 .. +3 (4 consecutive t).
  // With CH=16 each 16-row i-fragment IS one chunk: the q-lane scan alone
  // yields the chunk aggregate at q==3.
  const int M0 = blockIdx.x * 128;
  const int N0 = blockIdx.y * 128;
  #pragma unroll
  for (int j = 0; j < 4; ++j) {
    const int e = N0 + wN + j*16 + lr;
    const float bzv = bz[e];
    const float bhv = bh[e];
    float Aseg[4], Bseg[4];
    #pragma unroll
    for (int i = 0; i < 4; ++i) {
      const int mbase = M0 + wM + i*16 + q*4;
      float A = 1.0f, Bv = 0.0f;
      #pragma unroll
      for (int r = 0; r < 4; ++r) {
        const size_t idx = (size_t)(mbase + r)*DSZ + e;
        const float pz = accz[j][i][r] + bzv;
        const float ph = acch[j][i][r] + bhv;
        const float ex = __expf(-pz);
        const float z  = 1.0f / (1.0f + ex);
        const __bf16 abf = (__bf16)fmaf(ex, z, 1e-8f);  // (1-z) + 1e-8
        const float  af  = (float)abf;                   // rounded, matches pass3
        const float  bf  = z * ph;
        a_ws[idx]  = abf;
        b_out[idx] = bf;
        Bv = fmaf(af, Bv, bf);
        A *= af;
      }
      Aseg[i] = A; Bseg[i] = Bv;
    }
    // scan across the 4 q-lanes (stride 16) for each i: lane q ends with
    // composition of segments q'=0..q; q=3 holds the full 16-row chunk aggregate.
    #pragma unroll
    for (int i = 0; i < 4; ++i) {
      #pragma unroll
      for (int s = 16; s < 64; s <<= 1) {
        const float Ap = __shfl_up(Aseg[i], s, 64);
        const float Bp = __shfl_up(Bseg[i], s, 64);
        if (lane >= s) { Bseg[i] = fmaf(Aseg[i], Bp, Bseg[i]); Aseg[i] *= Ap; }
      }
    }
    if (q == 3) {
      #pragma unroll
      for (int i = 0; i < 4; ++i) {
        const int bc = (M0 + wM + i*16) >> 4;   // = b*NC + chunk (NC=256)
        Aprod[(size_t)bc*DSZ + e] = Aseg[i];
        Bcomp[(size_t)bc*DSZ + e] = Bseg[i];
      }
    }
  }
}

// ---------------- scan pass 2: wave64 shuffle scan, 4 chunks per lane --------
// one wave per (b,d); 4096 waves -> 1024 blocks of 256.
// NOTE: Hstart aliases Aprod in the launcher -- each thread reads its Ac[]
// cells before overwriting them, and threads touch disjoint addresses, so the
// alias is safe; Aprod/Hstart deliberately carry no __restrict__.
__global__ void scan_pass2_kernel(const float* Aprod,
                                  const float* __restrict__ Bcomp,
                                  float* Hstart)
{
  const int lane = threadIdx.x & 63;
  const int wave = (blockIdx.x * 256 + threadIdx.x) >> 6;  // 0..4095
  const int b = wave >> 10;
  const int d = wave & 1023;
  const size_t i0 = (size_t)(b*NC + 4*lane)*DSZ + d;
  float Ac[4], Bc[4];
  #pragma unroll
  for (int c = 0; c < 4; ++c) {
    Ac[c] = Aprod[i0 + (size_t)c*DSZ];
    Bc[c] = Bcomp[i0 + (size_t)c*DSZ];
  }
  // in-lane compose of the 4 chunks (in time order)
  float A = Ac[0], Bv = Bc[0];
  #pragma unroll
  for (int c = 1; c < 4; ++c) { Bv = fmaf(Ac[c], Bv, Bc[c]); A *= Ac[c]; }
  // wave-wide inclusive scan over lane groups
  #pragma unroll
  for (int s = 1; s < 64; s <<= 1) {
    const float Ap = __shfl_up(A,  s, 64);
    const float Bp = __shfl_up(Bv, s, 64);
    if (lane >= s) { Bv = fmaf(A, Bp, Bv); A *= Ap; }
  }
  float h = __shfl_up(Bv, 1, 64);  // exclusive: h at start of chunk 4*lane
  if (lane == 0) h = 0.0f;
  #pragma unroll
  for (int c = 0; c < 4; ++c) {
    Hstart[i0 + (size_t)c*DSZ] = h;
    h = fmaf(Ac[c], h, Bc[c]);
  }
}

// ---------------- scan pass 3: apply within chunk (4 d per thread) -----------
// CH=16: 1024 blocks (4 waves/SIMD) with a 16-step chain; loads fully
// unrolled so the 16 independent a/b loads issue ahead of the fma chain.
__global__ void scan_pass3_kernel(const __bf16* __restrict__ a_ws,
                                  const float* __restrict__ Hstart,
                                  float* __restrict__ out)
{
  const int bc   = blockIdx.x;               // 0..BSZ*NC-1
  const int d0   = threadIdx.x * 4;
  const size_t base = (size_t)bc * CH * DSZ + d0;
  float4 hv = *(const float4*)(Hstart + (size_t)bc*DSZ + d0);
  float h[4] = {hv.x, hv.y, hv.z, hv.w};
  #pragma unroll
  for (int t = 0; t < CH; ++t) {
    bf16x4 a4 = *(const bf16x4*)(a_ws + base + (size_t)t*DSZ);
    float4 b4 = *(const float4*)(out + base + (size_t)t*DSZ);
    const float bb[4] = {b4.x, b4.y, b4.z, b4.w};
    #pragma unroll
    for (int c = 0; c < 4; ++c)
      h[c] = fmaf((float)a4[c], h[c], bb[c]);
    *(float4*)(out + base + (size_t)t*DSZ) = make_float4(h[0], h[1], h[2], h[3]);
  }
}

extern "C" void kernel_launch(void* const* d_in, const int* in_sizes, int n_in,
                              void* d_out, int out_size, void* d_ws, size_t ws_size,
                              hipStream_t stream)
{
  const float* x  = (const float*)d_in[0];
  const float* Wz = (const float*)d_in[1];
  const float* bz = (const float*)d_in[2];
  const float* Wh = (const float*)d_in[3];
  const float* bh = (const float*)d_in[4];
  float* out = (float*)d_out;

  // ws layout: Xc (32MB) | Wzc (2MB) | Whc (2MB) | a (32MB) | Aprod (4MB) | Bcomp (4MB)
  // Hstart aliases Aprod (pass2 reads-then-overwrites its own cells only).
  __bf16* Xc   = (__bf16*)d_ws;
  __bf16* Wzc  = Xc  + (size_t)MSZ * DSZ;
  __bf16* Whc  = Wzc + (size_t)DSZ * DSZ;
  __bf16* a_ws = Whc + (size_t)DSZ * DSZ;
  float* Aprod  = (float*)(a_ws + (size_t)MSZ * DSZ);
  float* Bcomp  = Aprod + (size_t)BSZ*NC*DSZ;
  float* Hstart = Aprod;   // alias

  convert_tile_kernel<<<9216, 256, 0, stream>>>(x, Wz, Wh, Xc, Wzc, Whc);
  gemm_gate_kernel<<<dim3(MSZ/128, DSZ/128), 256, 0, stream>>>(
      Xc, Wzc, Whc, bz, bh, a_ws, out, Aprod, Bcomp);
  scan_pass2_kernel<<<(BSZ*DSZ)/4, 256, 0, stream>>>(Aprod, Bcomp, Hstart);
  scan_pass3_kernel<<<BSZ*NC, 256, 0, stream>>>(a_ws, Hstart, out);
}

// Round 2
// 241.327 us; speedup vs baseline: 1.0620x; 1.0620x over previous
//
#include <hip/hip_runtime.h>
#include <hip/hip_bf16.h>

// MinGRU forward: z=sigmoid(xWz^T), h~=xWh^T, a=1-z+1e-8, b=z*h~, scan h=a*h+b.
// B=4 T=4096 D=1024.
// R5: pass2 rewritten -- old version had lane=chunk => 4B loads at 16KB lane
// stride (64-line scatter per wave instruction, ~2M L3 transactions for 12MB
// of logical traffic). New version: one wave per (b, 64-d slice), lane=d =>
// every load/store is a single coalesced 256B transaction; serial over the
// 256 chunks with 16-deep register batching so load latency pipelines (the
// batch structure also keeps loads ahead of the aliased Hstart stores).
// GEMM kept at R4 structure (BK=64; measured at the m97-structure ceiling --
// BK tweaks don't move it; 8-phase 256^2 restructure is the next lever).

typedef __bf16 bf16x8 __attribute__((ext_vector_type(8)));
typedef __bf16 bf16x4 __attribute__((ext_vector_type(4)));
typedef float  f32x4  __attribute__((ext_vector_type(4)));

#define BSZ 4
#define TSZ 4096
#define DSZ 1024
#define MSZ (BSZ*TSZ)      // 16384 rows
#define CH  16             // scan chunk length
#define NC  (TSZ/CH)       // 256 chunks per sequence

__device__ __forceinline__ void gload_lds16(const __bf16* g, __bf16* l) {
  __builtin_amdgcn_global_load_lds(
      (const __attribute__((address_space(1))) void*)g,
      (__attribute__((address_space(3))) void*)l, 16, 0, 0);
}

// ---------------- conversion: fp32 row-major -> bf16 fragment-tiled ----------------
// tiled layout: [rowblk][kblk:32][i:8][l:64][j:8] where
//   row = rowblk*128 + i*16 + (l&15), k = kblk*32 + (l>>4)*8 + j
__global__ void convert_tile_kernel(const float* __restrict__ X,
                                    const float* __restrict__ Wz,
                                    const float* __restrict__ Wh,
                                    __bf16* __restrict__ Xc,
                                    __bf16* __restrict__ Wzc,
                                    __bf16* __restrict__ Whc)
{
  const int bx = blockIdx.x;
  const float* src; __bf16* dst; int gid;
  if (bx < 8192)      { src = X;  dst = Xc;  gid =  bx        *256 + threadIdx.x; }
  else if (bx < 8704) { src = Wz; dst = Wzc; gid = (bx - 8192)*256 + threadIdx.x; }
  else                { src = Wh; dst = Whc; gid = (bx - 8704)*256 + threadIdx.x; }
  const int l    = gid & 63;
  const int i    = (gid >> 6) & 7;
  const int kblk = (gid >> 9) & 31;
  const int rblk = gid >> 14;
  const int row  = rblk*128 + i*16 + (l & 15);
  const int col  = kblk*32 + (l >> 4)*8;
  const float* g = src + (size_t)row*DSZ + col;
  float4 v0 = *(const float4*)g;
  float4 v1 = *(const float4*)(g + 4);
  bf16x8 p;
  p[0]=(__bf16)v0.x; p[1]=(__bf16)v0.y; p[2]=(__bf16)v0.z; p[3]=(__bf16)v0.w;
  p[4]=(__bf16)v1.x; p[5]=(__bf16)v1.y; p[6]=(__bf16)v1.z; p[7]=(__bf16)v1.w;
  *(bf16x8*)(dst + (size_t)gid*8) = p;
}

// ---------------- GEMM + gate epilogue + fused per-chunk composition ------------
// block tile 128(M) x 128(N), BK=64; 256 threads = 4 waves in 2x2, each wave 64x64.
__global__ __launch_bounds__(256, 2) void gemm_gate_kernel(
    const __bf16* __restrict__ Xc,  const __bf16* __restrict__ Wzc,
    const __bf16* __restrict__ Whc,
    const float* __restrict__ bz, const float* __restrict__ bh,
    __bf16* __restrict__ a_ws, float* __restrict__ b_out,
    float* __restrict__ Aprod, float* __restrict__ Bcomp)
{
  __shared__ __align__(16) __bf16 As [8192];
  __shared__ __align__(16) __bf16 Bzs[8192];
  __shared__ __align__(16) __bf16 Bhs[8192];

  const int tid  = threadIdx.x;
  const int lane = tid & 63;
  const int wv   = tid >> 6;
  const int wM   = (wv >> 1) * 64;
  const int wN   = (wv & 1) * 64;
  const int wMg  = wM >> 4;
  const int wNg  = wN >> 4;
  const int lr   = lane & 15;
  const int q    = lane >> 4;
  const int wbase = wv * 64;           // wave-uniform

  const __bf16* Xb = Xc  + (size_t)blockIdx.x * 32 * 4096;
  const __bf16* Zb = Wzc + (size_t)blockIdx.y * 32 * 4096;
  const __bf16* Hb = Whc + (size_t)blockIdx.y * 32 * 4096;

  f32x4 accz[4][4] = {};
  f32x4 acch[4][4] = {};

  for (int kblk = 0; kblk < 16; ++kblk) {   // BK=64: two 32-wide k-slices per iter
    __syncthreads();
    const size_t tb = (size_t)kblk * 8192;
    #pragma unroll
    for (int c = 0; c < 4; ++c) {
      const int eo = (c*256 + wbase + lane) * 8;  // per-lane global elem offset
      const int lo = (c*256 + wbase) * 8;         // wave-uniform LDS elem offset
      gload_lds16(Xb + tb + eo, As  + lo);
      gload_lds16(Zb + tb + eo, Bzs + lo);
      gload_lds16(Hb + tb + eo, Bhs + lo);
    }
    __syncthreads();

    #pragma unroll
    for (int h = 0; h < 2; ++h) {
      const int ho = h * 4096;                    // select k-slice within LDS
      bf16x8 af[4];
      #pragma unroll
      for (int i = 0; i < 4; ++i)
        af[i] = *(const bf16x8*)(As + ho + (wMg + i)*512 + lane*8);
      #pragma unroll
      for (int j = 0; j < 4; ++j) {
        bf16x8 bz8 = *(const bf16x8*)(Bzs + ho + (wNg + j)*512 + lane*8);
        bf16x8 bh8 = *(const bf16x8*)(Bhs + ho + (wNg + j)*512 + lane*8);
        #pragma unroll
        for (int i = 0; i < 4; ++i) {
          accz[j][i] = __builtin_amdgcn_mfma_f32_16x16x32_bf16(af[i], bz8, accz[j][i], 0, 0, 0);
          acch[j][i] = __builtin_amdgcn_mfma_f32_16x16x32_bf16(af[i], bh8, acch[j][i], 0, 0, 0);
        }
      }
    }
  }

  // ---- epilogue: gate + store + fused per-chunk affine composition ----
  // C/D layout col=lane&15, row=(lane>>4)*4+reg (verified m89/m91).
  // Lane's 4 regs of tile i cover rows wM+i*16+q*4 .. +3 (4 consecutive t).
  // With CH=16 each 16-row i-fragment IS one chunk: the q-lane scan alone
  // yields the chunk aggregate at q==3.
  const int M0 = blockIdx.x * 128;
  const int N0 = blockIdx.y * 128;
  #pragma unroll
  for (int j = 0; j < 4; ++j) {
    const int e = N0 + wN + j*16 + lr;
    const float bzv = bz[e];
    const float bhv = bh[e];
    float Aseg[4], Bseg[4];
    #pragma unroll
    for (int i = 0; i < 4; ++i) {
      const int mbase = M0 + wM + i*16 + q*4;
      float A = 1.0f, Bv = 0.0f;
      #pragma unroll
      for (int r = 0; r < 4; ++r) {
        const size_t idx = (size_t)(mbase + r)*DSZ + e;
        const float pz = accz[j][i][r] + bzv;
        const float ph = acch[j][i][r] + bhv;
        const float ex = __expf(-pz);
        const float z  = 1.0f / (1.0f + ex);
        const __bf16 abf = (__bf16)fmaf(ex, z, 1e-8f);  // (1-z) + 1e-8
        const float  af  = (float)abf;                   // rounded, matches pass3
        const float  bf  = z * ph;
        a_ws[idx]  = abf;
        b_out[idx] = bf;
        Bv = fmaf(af, Bv, bf);
        A *= af;
      }
      Aseg[i] = A; Bseg[i] = Bv;
    }
    // scan across the 4 q-lanes (stride 16) for each i: lane q ends with
    // composition of segments q'=0..q; q=3 holds the full 16-row chunk aggregate.
    #pragma unroll
    for (int i = 0; i < 4; ++i) {
      #pragma unroll
      for (int s = 16; s < 64; s <<= 1) {
        const float Ap = __shfl_up(Aseg[i], s, 64);
        const float Bp = __shfl_up(Bseg[i], s, 64);
        if (lane >= s) { Bseg[i] = fmaf(Aseg[i], Bp, Bseg[i]); Aseg[i] *= Ap; }
      }
    }
    if (q == 3) {
      #pragma unroll
      for (int i = 0; i < 4; ++i) {
        const int bc = (M0 + wM + i*16) >> 4;   // = b*NC + chunk (NC=256)
        Aprod[(size_t)bc*DSZ + e] = Aseg[i];
        Bcomp[(size_t)bc*DSZ + e] = Bseg[i];
      }
    }
  }
}

// ---------------- scan pass 2: lane = d (coalesced), serial over chunks ------
// One wave per (b, 64-d slice): 4 b x 16 slices = 64 waves, one per block.
// Dependent chain is only 256 fma pairs (~1K cycles); loads batched 16 deep
// in registers so L2/L3 latency pipelines. All accesses are full 256B
// wave-coalesced transactions (old version: 4B per lane at 16KB stride).
// Hstart aliases Aprod in the launcher: within a batch all A/B loads issue
// BEFORE any Hstart store, and each (b,c,d) cell is touched by exactly one
// thread, so the alias is safe; Aprod/Hstart carry no __restrict__.
#define P2B 16   // batch depth (NC/P2B = 16 batches)
__global__ void scan_pass2_kernel(const float* Aprod,
                                  const float* __restrict__ Bcomp,
                                  float* Hstart)
{
  const int lane = threadIdx.x & 63;
  const int b    = blockIdx.x >> 4;          // 0..3
  const int d    = (blockIdx.x & 15) * 64 + lane;
  const size_t base = (size_t)b * NC * DSZ + d;
  float h = 0.0f;
  for (int c0 = 0; c0 < NC; c0 += P2B) {
    float Ar[P2B], Br[P2B];
    #pragma unroll
    for (int c = 0; c < P2B; ++c) {
      Ar[c] = Aprod[base + (size_t)(c0 + c)*DSZ];
      Br[c] = Bcomp[base + (size_t)(c0 + c)*DSZ];
    }
    #pragma unroll
    for (int c = 0; c < P2B; ++c) {
      Hstart[base + (size_t)(c0 + c)*DSZ] = h;
      h = fmaf(Ar[c], h, Br[c]);
    }
  }
}

// ---------------- scan pass 3: apply within chunk (4 d per thread) -----------
// CH=16: 1024 blocks (4 waves/SIMD) with a 16-step chain; loads fully
// unrolled so the 16 independent a/b loads issue ahead of the fma chain.
__global__ void scan_pass3_kernel(const __bf16* __restrict__ a_ws,
                                  const float* __restrict__ Hstart,
                                  float* __restrict__ out)
{
  const int bc   = blockIdx.x;               // 0..BSZ*NC-1
  const int d0   = threadIdx.x * 4;
  const size_t base = (size_t)bc * CH * DSZ + d0;
  float4 hv = *(const float4*)(Hstart + (size_t)bc*DSZ + d0);
  float h[4] = {hv.x, hv.y, hv.z, hv.w};
  #pragma unroll
  for (int t = 0; t < CH; ++t) {
    bf16x4 a4 = *(const bf16x4*)(a_ws + base + (size_t)t*DSZ);
    float4 b4 = *(const float4*)(out + base + (size_t)t*DSZ);
    const float bb[4] = {b4.x, b4.y, b4.z, b4.w};
    #pragma unroll
    for (int c = 0; c < 4; ++c)
      h[c] = fmaf((float)a4[c], h[c], bb[c]);
    *(float4*)(out + base + (size_t)t*DSZ) = make_float4(h[0], h[1], h[2], h[3]);
  }
}

extern "C" void kernel_launch(void* const* d_in, const int* in_sizes, int n_in,
                              void* d_out, int out_size, void* d_ws, size_t ws_size,
                              hipStream_t stream)
{
  const float* x  = (const float*)d_in[0];
  const float* Wz = (const float*)d_in[1];
  const float* bz = (const float*)d_in[2];
  const float* Wh = (const float*)d_in[3];
  const float* bh = (const float*)d_in[4];
  float* out = (float*)d_out;

  // ws layout: Xc (32MB) | Wzc (2MB) | Whc (2MB) | a (32MB) | Aprod (4MB) | Bcomp (4MB)
  // Hstart aliases Aprod (pass2 reads each cell before overwriting it).
  __bf16* Xc   = (__bf16*)d_ws;
  __bf16* Wzc  = Xc  + (size_t)MSZ * DSZ;
  __bf16* Whc  = Wzc + (size_t)DSZ * DSZ;
  __bf16* a_ws = Whc + (size_t)DSZ * DSZ;
  float* Aprod  = (float*)(a_ws + (size_t)MSZ * DSZ);
  float* Bcomp  = Aprod + (size_t)BSZ*NC*DSZ;
  float* Hstart = Aprod;   // alias

  convert_tile_kernel<<<9216, 256, 0, stream>>>(x, Wz, Wh, Xc, Wzc, Whc);
  gemm_gate_kernel<<<dim3(MSZ/128, DSZ/128), 256, 0, stream>>>(
      Xc, Wzc, Whc, bz, bh, a_ws, out, Aprod, Bcomp);
  scan_pass2_kernel<<<64, 64, 0, stream>>>(Aprod, Bcomp, Hstart);
  scan_pass3_kernel<<<BSZ*NC, 256, 0, stream>>>(a_ws, Hstart, out);
}